// Round 8
// baseline (335.089 us; speedup 1.0000x reference)
//
#include <hip/hip_runtime.h>

// ---------------------------------------------------------------------------
// GCN forward, bf16-MFMA + int8-gather edition.
//   x -> bf16 (fused pre-pass); 3x (bf16 MFMA GEMM -> int8 T + per-(row,half)
//   scale; CSR sym-norm agg (int8 gather, fp32 accum) + bias + relu -> bf16)
//   collapsed layer 4: pooled = (sum_u s_u*h3[u]) @ W4 + N*b4; log_softmax.
// R12: gload_lds+swizzle -> 312.0. R13/14/15: agg restructures FAILED.
// R17: int8 T -> 314 but exposed GEMM 42us, MfmaUtil 5.4%, latency-bound.
// R18: dbuf 2-phase + XCD-pair + xb pre-convert -> 306.6; GEMM only ~38us:
//      per-K-step compute (~300cy) << staged-load latency (~900cy); 2-phase
//      can't hide it (arithmetic in journal).
// R19: single-shot GEMM for tiny K: FULL A panel (128x256 bf16 = 64KB, the
//      whole K) staged via 16 gload_lds/wave, ONE barrier, then 8 K-chunks
//      of {ds_read + B-from-global(L2) + 16 MFMA} with no barriers at all.
//      B skips LDS entirely (Wt is L2-resident, every byte consumed).
//      Latency exposed once per block instead of per K-step.
// ---------------------------------------------------------------------------

typedef __attribute__((ext_vector_type(8))) short short8;
typedef __attribute__((ext_vector_type(8))) signed char schar8;
typedef __attribute__((ext_vector_type(4))) float float4v;

__device__ __forceinline__ unsigned short f2b(float f) {
    unsigned int u = __builtin_bit_cast(unsigned int, f);
    u += 0x7fffu + ((u >> 16) & 1u);   // round-to-nearest-even
    return (unsigned short)(u >> 16);
}
__device__ __forceinline__ float b2f(unsigned short b) {
    unsigned int u = ((unsigned int)b) << 16;
    return __builtin_bit_cast(float, u);
}

// ---------------- fused zero + weight conversion + x->bf16 ----------------
__global__ void zero_convert_kernel(int* __restrict__ cnt, float* __restrict__ tsum,
                                    float* __restrict__ accbuf,
                                    const float* __restrict__ W1, const float* __restrict__ W2,
                                    const float* __restrict__ W3, unsigned short* __restrict__ Wt1,
                                    unsigned short* __restrict__ Wt2, unsigned short* __restrict__ Wt3,
                                    const float* __restrict__ x, unsigned short* __restrict__ xb,
                                    int N, int nb) {
    int t = threadIdx.x;
    int b = blockIdx.x;
    if (b < nb) {
        int i = b * 256 + t;
        if (i < N) { cnt[i] = 0; tsum[i] = 0.f; }
        if (b == 0) accbuf[t] = 0.f;
    } else if (b < nb + 768) {
        int bb = b - nb;
        int w = bb >> 8;
        int n = bb & 255;
        const float* W = (w == 0) ? W1 : (w == 1) ? W2 : W3;
        unsigned short* Wt = (w == 0) ? Wt1 : (w == 1) ? Wt2 : Wt3;
        Wt[n * 256 + t] = f2b(W[t * 256 + n]);
    } else {
        size_t base = ((size_t)(b - nb - 768) * 256 + t) * 8;
        if (base < (size_t)N * 256) {
            float4 lo = *(const float4*)&x[base];
            float4 hi = *(const float4*)&x[base + 4];
            uint4 o;
            o.x = (unsigned int)f2b(lo.x) | ((unsigned int)f2b(lo.y) << 16);
            o.y = (unsigned int)f2b(lo.z) | ((unsigned int)f2b(lo.w) << 16);
            o.z = (unsigned int)f2b(hi.x) | ((unsigned int)f2b(hi.y) << 16);
            o.w = (unsigned int)f2b(hi.z) | ((unsigned int)f2b(hi.w) << 16);
            *(uint4*)&xb[base] = o;
        }
    }
}

__global__ void count_kernel(const int* __restrict__ dst, int* __restrict__ cnt, int E) {
    int i = blockIdx.x * blockDim.x + threadIdx.x;
    if (i < E) atomicAdd(&cnt[dst[i]], 1);
}

__global__ void blocksum_kernel(const int* __restrict__ cnt, int* __restrict__ bsum, int N) {
    __shared__ int s[256];
    int t = threadIdx.x;
    int i = blockIdx.x * 256 + t;
    s[t] = (i < N) ? cnt[i] : 0;
    __syncthreads();
    for (int d = 128; d > 0; d >>= 1) {
        if (t < d) s[t] += s[t + d];
        __syncthreads();
    }
    if (t == 0) bsum[blockIdx.x] = s[0];
}

__global__ void finalize_kernel(const int* __restrict__ cnt, const int* __restrict__ bsum,
                                int* __restrict__ offs, int* __restrict__ cursor,
                                float* __restrict__ dis, int N, int E, int nb) {
    __shared__ int bs[256];
    __shared__ int s[256];
    int t = threadIdx.x;
    bs[t] = (t < nb) ? bsum[t] : 0;
    __syncthreads();
    for (int d = 1; d < 256; d <<= 1) {
        int x = (t >= d) ? bs[t - d] : 0;
        __syncthreads();
        bs[t] += x;
        __syncthreads();
    }
    int blockoff = (blockIdx.x == 0) ? 0 : bs[blockIdx.x - 1];
    int i = blockIdx.x * 256 + t;
    int c = (i < N) ? cnt[i] : 0;
    s[t] = c;
    __syncthreads();
    for (int d = 1; d < 256; d <<= 1) {
        int x = (t >= d) ? s[t - d] : 0;
        __syncthreads();
        s[t] += x;
        __syncthreads();
    }
    if (i < N) {
        int ex = blockoff + s[t] - c;
        offs[i] = ex;
        cursor[i] = ex;
        dis[i] = rsqrtf((float)(c + 1));
    }
    if (blockIdx.x == 0 && t == 0) offs[N] = E;
}

__global__ void scatter_outsum_kernel(const int* __restrict__ src, const int* __restrict__ dst,
                                      const float* __restrict__ dis, int* __restrict__ cursor,
                                      int* __restrict__ csr_src, float* __restrict__ csr_nrm,
                                      float* __restrict__ tsum, int E) {
    int i = blockIdx.x * blockDim.x + threadIdx.x;
    if (i < E) {
        int s = src[i], d = dst[i];
        float dd = dis[d];
        int pos = atomicAdd(&cursor[d], 1);
        csr_src[pos] = s;
        csr_nrm[pos] = dis[s] * dd;
        atomicAdd(&tsum[s], dd);
    }
}

// ---------------- bf16 MFMA GEMM -> int8 (R19: single-shot full-K) ----------
// C8[M,256] = quant(A[M,256] @ W[256,256]); Ts[row][half] = rowmax/127.
// LDS: FULL A panel [128][256] bf16 = 64KB (exact static limit), XOR-swizzled
// per 16B slot: mem_slot = content_slot ^ (row&7); gload_lds source
// pre-swizzled (rule 21). B (Wt) read directly from global (L2-resident).
// One __syncthreads after staging; barrier-free MFMA phase (compiler free to
// pipeline B-loads under MFMA). 1-D XCD-paired grid as R18. 2 blocks/CU.
__global__ __launch_bounds__(256, 2) void gemm_bf16_kernel(
        const unsigned short* __restrict__ Ab, const unsigned short* __restrict__ Wt,
        signed char* __restrict__ C8, float* __restrict__ Ts, int M) {
    __shared__ unsigned short As[128 * 256];   // 64 KB
    const int tid = threadIdx.x;
    const int lane = tid & 63;
    const int wave = tid >> 6;
    const int l15 = lane & 15;
    const int quad = lane >> 4;
    const int wm = wave & 1;
    const int wn = wave >> 1;

    const int bid = blockIdx.x;
    const int grp = bid >> 4;
    const int ii = bid & 15;
    const int xv = grp * 8 + (ii & 7);
    const int yv = ii >> 3;
    const int m0 = xv * 128;
    const int n0 = yv * 128;
    if (m0 >= M) return;

    float4v acc[4][4] = {};

    // ---- stage full A panel: 16 gload_lds per wave, 2 rows (1KB) each ----
    // lane l -> row r0 + (l>>5), mem slot (l&31); content there = slot^(row&7)
    const int rl = lane >> 5;
    const int sc = lane & 31;
#pragma unroll
    for (int i = 0; i < 16; i++) {
        int r0 = wave * 32 + i * 2;
        int row = r0 + rl;
        int gm = m0 + row;
        if (gm >= M) gm = M - 1;          // clamp; garbage rows masked at store
        const unsigned short* gp = &Ab[(size_t)gm * 256 + 8 * (sc ^ (row & 7))];
        __builtin_amdgcn_global_load_lds(
            (const __attribute__((address_space(1))) unsigned int*)gp,
            (__attribute__((address_space(3))) unsigned int*)&As[r0 * 256],
            16, 0, 0);
    }
    __syncthreads();

    // ---- barrier-free compute: 8 K-chunks of 32 ----
    const unsigned short* Bt = Wt + (size_t)n0 * 256;
#pragma unroll
    for (int kc = 0; kc < 256; kc += 32) {
        const int sl = (kc >> 3) + quad;       // 16B content slot 0..31
        short8 af[4], bf[4];
#pragma unroll
        for (int mi = 0; mi < 4; mi++) {
            int row = wm * 64 + mi * 16 + l15;
            af[mi] = *(const short8*)&As[row * 256 + 8 * (sl ^ (row & 7))];
        }
#pragma unroll
        for (int nj = 0; nj < 4; nj++) {
            int row = wn * 64 + nj * 16 + l15;
            bf[nj] = *(const short8*)&Bt[(size_t)row * 256 + kc + quad * 8];
        }
#pragma unroll
        for (int mi = 0; mi < 4; mi++)
#pragma unroll
            for (int nj = 0; nj < 4; nj++)
                acc[mi][nj] = __builtin_amdgcn_mfma_f32_16x16x32_bf16(
                    af[mi], bf[nj], acc[mi][nj], 0, 0, 0);
    }
    __syncthreads();   // done reading As; epilogue reuses it

    // ---- epilogue: per-row absmax over this block's 128 cols -> int8 ----
    float* pmax = (float*)As;              // [128][2]
    float* pinv = (float*)&As[2048];       // [128]
#pragma unroll
    for (int mi = 0; mi < 4; mi++) {
#pragma unroll
        for (int r = 0; r < 4; r++) {
            float m = fabsf(acc[mi][0][r]);
            m = fmaxf(m, fabsf(acc[mi][1][r]));
            m = fmaxf(m, fabsf(acc[mi][2][r]));
            m = fmaxf(m, fabsf(acc[mi][3][r]));
            m = fmaxf(m, __shfl_xor(m, 1));
            m = fmaxf(m, __shfl_xor(m, 2));
            m = fmaxf(m, __shfl_xor(m, 4));
            m = fmaxf(m, __shfl_xor(m, 8));
            if (l15 == 0) pmax[(wm * 64 + mi * 16 + quad * 4 + r) * 2 + wn] = m;
        }
    }
    __syncthreads();
    if (tid < 128) {
        float m = fmaxf(pmax[tid * 2], pmax[tid * 2 + 1]);
        int grow = m0 + tid;
        if (grow < M) Ts[(size_t)grow * 2 + yv] = m * (1.f / 127.f);
        pinv[tid] = (m > 0.f) ? 127.f / m : 0.f;
    }
    __syncthreads();
#pragma unroll
    for (int mi = 0; mi < 4; mi++) {
#pragma unroll
        for (int r = 0; r < 4; r++) {
            int lr = wm * 64 + mi * 16 + quad * 4 + r;
            float inv = pinv[lr];
            int row = m0 + lr;
            if (row < M) {
#pragma unroll
                for (int nj = 0; nj < 4; nj++) {
                    int col = n0 + wn * 64 + nj * 16 + l15;
                    C8[(size_t)row * 256 + col] =
                        (signed char)__float2int_rn(acc[mi][nj][r] * inv);
                }
            }
        }
    }
}

// ---------------- aggregation (int8 gather, fp32 accum, bf16 out) ----------
template <int RELU>
__global__ __launch_bounds__(256) void agg_bf16_kernel(
        const signed char* __restrict__ T8, const float* __restrict__ Ts,
        const float* __restrict__ bias,
        const int* __restrict__ offs, const int* __restrict__ csr_src,
        const float* __restrict__ csr_nrm, const float* __restrict__ dis,
        unsigned short* __restrict__ out, int N) {
    int hw = threadIdx.x >> 5;                 // half-wave 0..7
    int l = threadIdx.x & 31;
    int v = blockIdx.x * 8 + hw;
    if (v >= N) return;
    int f8 = l * 8;
    int hh = l >> 4;                           // column half 0/1
    int beg = offs[v], end = offs[v + 1];
    float dv = dis[v];
    float w = dv * dv * Ts[(size_t)v * 2 + hh];
    float a[8];
    {
        schar8 q = *(const schar8*)&T8[(size_t)v * 256 + f8];
#pragma unroll
        for (int i = 0; i < 8; i++) a[i] = w * (float)q[i];
    }
    int e = beg;
    for (; e + 4 <= end; e += 4) {
        int s0 = csr_src[e],     s1 = csr_src[e + 1];
        int s2 = csr_src[e + 2], s3 = csr_src[e + 3];
        float n0 = csr_nrm[e]     * Ts[(size_t)s0 * 2 + hh];
        float n1 = csr_nrm[e + 1] * Ts[(size_t)s1 * 2 + hh];
        float n2 = csr_nrm[e + 2] * Ts[(size_t)s2 * 2 + hh];
        float n3 = csr_nrm[e + 3] * Ts[(size_t)s3 * 2 + hh];
        schar8 h0 = *(const schar8*)&T8[(size_t)s0 * 256 + f8];
        schar8 h1 = *(const schar8*)&T8[(size_t)s1 * 256 + f8];
        schar8 h2 = *(const schar8*)&T8[(size_t)s2 * 256 + f8];
        schar8 h3 = *(const schar8*)&T8[(size_t)s3 * 256 + f8];
#pragma unroll
        for (int i = 0; i < 8; i++)
            a[i] += n0 * (float)h0[i] + n1 * (float)h1[i]
                  + n2 * (float)h2[i] + n3 * (float)h3[i];
    }
    for (; e < end; e++) {
        int s = csr_src[e];
        float nm = csr_nrm[e] * Ts[(size_t)s * 2 + hh];
        schar8 h = *(const schar8*)&T8[(size_t)s * 256 + f8];
#pragma unroll
        for (int i = 0; i < 8; i++) a[i] += nm * (float)h[i];
    }
    float4 bv0 = *(const float4*)&bias[f8];
    float4 bv1 = *(const float4*)&bias[f8 + 4];
    a[0] += bv0.x; a[1] += bv0.y; a[2] += bv0.z; a[3] += bv0.w;
    a[4] += bv1.x; a[5] += bv1.y; a[6] += bv1.z; a[7] += bv1.w;
    if (RELU) {
#pragma unroll
        for (int i = 0; i < 8; i++) a[i] = fmaxf(a[i], 0.f);
    }
    uint4 o;
    o.x = (unsigned int)f2b(a[0]) | ((unsigned int)f2b(a[1]) << 16);
    o.y = (unsigned int)f2b(a[2]) | ((unsigned int)f2b(a[3]) << 16);
    o.z = (unsigned int)f2b(a[4]) | ((unsigned int)f2b(a[5]) << 16);
    o.w = (unsigned int)f2b(a[6]) | ((unsigned int)f2b(a[7]) << 16);
    *(uint4*)&out[(size_t)v * 256 + f8] = o;
}

// ---------------- weighted pool, two-stage (R12 proven) ----------------
__global__ __launch_bounds__(256) void wpool_partial(
        const unsigned short* __restrict__ H, const float* __restrict__ dis,
        const float* __restrict__ tsum, float* __restrict__ partial, int N) {
    int tid = threadIdx.x;
    int f8 = (tid & 31) * 8;
    int rg = tid >> 5;
    float a[8] = {};
    for (int r = blockIdx.x * 8 + rg; r < N; r += gridDim.x * 8) {
        float s = dis[r] * (dis[r] + tsum[r]);
        short8 h = *(const short8*)&H[(size_t)r * 256 + f8];
#pragma unroll
        for (int i = 0; i < 8; i++) a[i] += s * b2f((unsigned short)h[i]);
    }
    __shared__ float red[8 * 256];
#pragma unroll
    for (int i = 0; i < 8; i++) red[rg * 256 + f8 + i] = a[i];
    __syncthreads();
    for (int s = 4; s > 0; s >>= 1) {
        if (rg < s) {
#pragma unroll
            for (int i = 0; i < 8; i++)
                red[rg * 256 + f8 + i] += red[(rg + s) * 256 + f8 + i];
        }
        __syncthreads();
    }
    partial[(size_t)blockIdx.x * 256 + tid] = red[tid];
}

__global__ void wpool_reduce(const float* __restrict__ partial, float* __restrict__ acc) {
    int f = threadIdx.x;
    int p0 = blockIdx.x * 32;
    float a = 0.f;
#pragma unroll
    for (int p = 0; p < 32; p++) a += partial[(size_t)(p0 + p) * 256 + f];
    atomicAdd(&acc[f], a);
}

__global__ void final_kernel(const float* __restrict__ acc, const float* __restrict__ W4,
                             const float* __restrict__ b4, float* __restrict__ out, int N) {
    __shared__ float red[128];
    int c = threadIdx.x;
    float p = (float)N * b4[c];
    for (int k = 0; k < 256; k++) p += acc[k] * W4[k * 128 + c];
    out[c] = p;
    red[c] = p;
    __syncthreads();
    for (int s = 64; s > 0; s >>= 1) {
        if (c < s) red[c] = fmaxf(red[c], red[c + s]);
        __syncthreads();
    }
    float m = red[0];
    __syncthreads();
    red[c] = expf(p - m);
    __syncthreads();
    for (int s = 64; s > 0; s >>= 1) {
        if (c < s) red[c] += red[c + s];
        __syncthreads();
    }
    float lse = m + logf(red[0]);
    out[128 + c] = p - lse;
}

extern "C" void kernel_launch(void* const* d_in, const int* in_sizes, int n_in,
                              void* d_out, int out_size, void* d_ws, size_t ws_size,
                              hipStream_t stream) {
    const float* x  = (const float*)d_in[0];
    const int*   ei = (const int*)d_in[1];
    const float* W1 = (const float*)d_in[2];
    const float* b1 = (const float*)d_in[3];
    const float* W2 = (const float*)d_in[4];
    const float* b2 = (const float*)d_in[5];
    const float* W3 = (const float*)d_in[6];
    const float* b3 = (const float*)d_in[7];
    const float* W4 = (const float*)d_in[8];
    const float* b4 = (const float*)d_in[9];

    const int N = in_sizes[0] / 256;
    const int E = in_sizes[1] / 2;
    const int* src = ei;
    const int* dst = ei + E;

    char* p = (char*)d_ws;
    auto alloc = [&](size_t bytes) {
        char* r = p;
        p += (bytes + 255) & ~(size_t)255;
        return r;
    };
    int*            cnt     = (int*)alloc((size_t)N * 4);
    int*            offs    = (int*)alloc((size_t)(N + 1) * 4);
    int*            cursor  = (int*)alloc((size_t)N * 4);
    float*          dis     = (float*)alloc((size_t)N * 4);
    float*          tsum    = (float*)alloc((size_t)N * 4);
    int*            bsum    = (int*)alloc(1024 * 4);
    int*            csr_src = (int*)alloc((size_t)E * 4);
    float*          csr_nrm = (float*)alloc((size_t)E * 4);
    unsigned short* Wt1     = (unsigned short*)alloc(256 * 256 * 2);
    unsigned short* Wt2     = (unsigned short*)alloc(256 * 256 * 2);
    unsigned short* Wt3     = (unsigned short*)alloc(256 * 256 * 2);
    unsigned short* xb      = (unsigned short*)alloc((size_t)N * 256 * 2);
    signed char*    T8      = (signed char*)alloc((size_t)N * 256);
    float*          Ts      = (float*)alloc((size_t)N * 2 * 4);
    unsigned short* Abuf    = (unsigned short*)alloc((size_t)N * 256 * 2);
    float*          partial = (float*)alloc((size_t)1024 * 256 * 4);
    float*          accbuf  = (float*)alloc(256 * 4);

    // ---- graph preprocessing + dtype conversion ----
    int eb = (E + 255) / 256;
    int nb = (N + 255) / 256;  // 196; finalize's bsum scan assumes nb <= 256
    int ncvt = (N * 32 + 255) / 256;   // x->bf16, 8 elems/thread
    zero_convert_kernel<<<nb + 768 + ncvt, 256, 0, stream>>>(
        cnt, tsum, accbuf, W1, W2, W3, Wt1, Wt2, Wt3, x, xb, N, nb);
    count_kernel<<<eb, 256, 0, stream>>>(dst, cnt, E);
    blocksum_kernel<<<nb, 256, 0, stream>>>(cnt, bsum, N);
    finalize_kernel<<<nb, 256, 0, stream>>>(cnt, bsum, offs, cursor, dis, N, E, nb);
    scatter_outsum_kernel<<<eb, 256, 0, stream>>>(src, dst, dis, cursor, csr_src,
                                                  csr_nrm, tsum, E);

    // ---- layers 1..3 ----
    int mtiles = (N + 127) / 128;            // 391
    int ggrid = ((mtiles + 7) / 8) * 16;     // XCD-paired 1-D grid (784)
    int ab = (N + 7) / 8;
    gemm_bf16_kernel<<<ggrid, 256, 0, stream>>>(xb, Wt1, T8, Ts, N);
    agg_bf16_kernel<1><<<ab, 256, 0, stream>>>(T8, Ts, b1, offs, csr_src, csr_nrm, dis, Abuf, N);
    gemm_bf16_kernel<<<ggrid, 256, 0, stream>>>(Abuf, Wt2, T8, Ts, N);
    agg_bf16_kernel<1><<<ab, 256, 0, stream>>>(T8, Ts, b2, offs, csr_src, csr_nrm, dis, Abuf, N);
    gemm_bf16_kernel<<<ggrid, 256, 0, stream>>>(Abuf, Wt3, T8, Ts, N);
    agg_bf16_kernel<1><<<ab, 256, 0, stream>>>(T8, Ts, b3, offs, csr_src, csr_nrm, dis, Abuf, N);

    // ---- collapsed layer 4 + pool + log_softmax ----
    wpool_partial<<<1024, 256, 0, stream>>>(Abuf, dis, tsum, partial, N);
    wpool_reduce<<<32, 256, 0, stream>>>(partial, accbuf);
    final_kernel<<<1, 128, 0, stream>>>(accbuf, W4, b4, (float*)d_out, N);
}

// Round 9
// 291.972 us; speedup vs baseline: 1.1477x; 1.1477x over previous
//
#include <hip/hip_runtime.h>

// ---------------------------------------------------------------------------
// GCN forward, bf16-MFMA + int8-gather edition.
//   x -> bf16 (fused pre-pass); 3x (bf16 MFMA GEMM -> int8 T + per-(row,half)
//   scale; CSR sym-norm agg (int8 gather, fp32 accum) + bias + relu -> bf16)
//   collapsed layer 4: pooled = (sum_u s_u*h3[u]) @ W4 + N*b4; log_softmax.
// R12: gload_lds+swizzle -> 312.0. R13/14/15: agg restructures FAILED.
// R17: int8 T -> 314; exposed GEMM 42us: MfmaUtil 5.4%, HBM 19%, Occ 19%
//      -> ALL low = latency/occupancy-bound (roofline table row 3).
// R18: dbuf 2-phase + XCD-pair + xb pre-convert -> 306.6 (best). Pipeline at
//      2 blocks/CU only bought ~10%.
// R19 (FAILED +28): single-shot full-K staging -> serial 64KB drain + B-in-
//      dependence-chain. Reverted.
// R20: occupancy play (the untried axis): tile 64x128, single-buf BK=64,
//      LDS 24KB, launch_bounds(256,5) -> 5-6 blocks/CU (~20-24 waves/CU,
//      3x R18); grid 1568 XCD-paired. Cross-block wave overlap (m114) hides
//      staging instead of explicit pipelining.
// ---------------------------------------------------------------------------

typedef __attribute__((ext_vector_type(8))) short short8;
typedef __attribute__((ext_vector_type(8))) signed char schar8;
typedef __attribute__((ext_vector_type(4))) float float4v;

__device__ __forceinline__ unsigned short f2b(float f) {
    unsigned int u = __builtin_bit_cast(unsigned int, f);
    u += 0x7fffu + ((u >> 16) & 1u);   // round-to-nearest-even
    return (unsigned short)(u >> 16);
}
__device__ __forceinline__ float b2f(unsigned short b) {
    unsigned int u = ((unsigned int)b) << 16;
    return __builtin_bit_cast(float, u);
}

// ---------------- fused zero + weight conversion + x->bf16 ----------------
__global__ void zero_convert_kernel(int* __restrict__ cnt, float* __restrict__ tsum,
                                    float* __restrict__ accbuf,
                                    const float* __restrict__ W1, const float* __restrict__ W2,
                                    const float* __restrict__ W3, unsigned short* __restrict__ Wt1,
                                    unsigned short* __restrict__ Wt2, unsigned short* __restrict__ Wt3,
                                    const float* __restrict__ x, unsigned short* __restrict__ xb,
                                    int N, int nb) {
    int t = threadIdx.x;
    int b = blockIdx.x;
    if (b < nb) {
        int i = b * 256 + t;
        if (i < N) { cnt[i] = 0; tsum[i] = 0.f; }
        if (b == 0) accbuf[t] = 0.f;
    } else if (b < nb + 768) {
        int bb = b - nb;
        int w = bb >> 8;
        int n = bb & 255;
        const float* W = (w == 0) ? W1 : (w == 1) ? W2 : W3;
        unsigned short* Wt = (w == 0) ? Wt1 : (w == 1) ? Wt2 : Wt3;
        Wt[n * 256 + t] = f2b(W[t * 256 + n]);
    } else {
        size_t base = ((size_t)(b - nb - 768) * 256 + t) * 8;
        if (base < (size_t)N * 256) {
            float4 lo = *(const float4*)&x[base];
            float4 hi = *(const float4*)&x[base + 4];
            uint4 o;
            o.x = (unsigned int)f2b(lo.x) | ((unsigned int)f2b(lo.y) << 16);
            o.y = (unsigned int)f2b(lo.z) | ((unsigned int)f2b(lo.w) << 16);
            o.z = (unsigned int)f2b(hi.x) | ((unsigned int)f2b(hi.y) << 16);
            o.w = (unsigned int)f2b(hi.z) | ((unsigned int)f2b(hi.w) << 16);
            *(uint4*)&xb[base] = o;
        }
    }
}

__global__ void count_kernel(const int* __restrict__ dst, int* __restrict__ cnt, int E) {
    int i = blockIdx.x * blockDim.x + threadIdx.x;
    if (i < E) atomicAdd(&cnt[dst[i]], 1);
}

__global__ void blocksum_kernel(const int* __restrict__ cnt, int* __restrict__ bsum, int N) {
    __shared__ int s[256];
    int t = threadIdx.x;
    int i = blockIdx.x * 256 + t;
    s[t] = (i < N) ? cnt[i] : 0;
    __syncthreads();
    for (int d = 128; d > 0; d >>= 1) {
        if (t < d) s[t] += s[t + d];
        __syncthreads();
    }
    if (t == 0) bsum[blockIdx.x] = s[0];
}

__global__ void finalize_kernel(const int* __restrict__ cnt, const int* __restrict__ bsum,
                                int* __restrict__ offs, int* __restrict__ cursor,
                                float* __restrict__ dis, int N, int E, int nb) {
    __shared__ int bs[256];
    __shared__ int s[256];
    int t = threadIdx.x;
    bs[t] = (t < nb) ? bsum[t] : 0;
    __syncthreads();
    for (int d = 1; d < 256; d <<= 1) {
        int x = (t >= d) ? bs[t - d] : 0;
        __syncthreads();
        bs[t] += x;
        __syncthreads();
    }
    int blockoff = (blockIdx.x == 0) ? 0 : bs[blockIdx.x - 1];
    int i = blockIdx.x * 256 + t;
    int c = (i < N) ? cnt[i] : 0;
    s[t] = c;
    __syncthreads();
    for (int d = 1; d < 256; d <<= 1) {
        int x = (t >= d) ? s[t - d] : 0;
        __syncthreads();
        s[t] += x;
        __syncthreads();
    }
    if (i < N) {
        int ex = blockoff + s[t] - c;
        offs[i] = ex;
        cursor[i] = ex;
        dis[i] = rsqrtf((float)(c + 1));
    }
    if (blockIdx.x == 0 && t == 0) offs[N] = E;
}

__global__ void scatter_outsum_kernel(const int* __restrict__ src, const int* __restrict__ dst,
                                      const float* __restrict__ dis, int* __restrict__ cursor,
                                      int* __restrict__ csr_src, float* __restrict__ csr_nrm,
                                      float* __restrict__ tsum, int E) {
    int i = blockIdx.x * blockDim.x + threadIdx.x;
    if (i < E) {
        int s = src[i], d = dst[i];
        float dd = dis[d];
        int pos = atomicAdd(&cursor[d], 1);
        csr_src[pos] = s;
        csr_nrm[pos] = dis[s] * dd;
        atomicAdd(&tsum[s], dd);
    }
}

// ---------------- bf16 MFMA GEMM -> int8 (R20: 64x128, high occupancy) -------
// C8[M,256] = quant(A[M,256] @ W[256,256]); Ts[row][half] = rowmax/127.
// Tile 64(M)x128(N), BK=64, single-buffered LDS 24KB (A 8KB + B 16KB).
// 4 waves: wm=wave&1 (32 rows), wn=wave>>1 (64 cols); acc[2][4].
// launch_bounds(256,5) -> 5 blocks/CU (20 waves). Grid 1-D XCD-paired:
// grp=bid>>4, i=bid&15, xv=grp*8+(i&7), yv=i>>3 (col halves 8 bids apart ->
// same XCD -> A L2-shared). LDS rows 128B, XOR slot swizzle (slot^=(row&7));
// gload_lds source pre-swizzled (rule 21) -> conflict-free ds_read_b128.
__global__ __launch_bounds__(256, 5) void gemm_bf16_kernel(
        const unsigned short* __restrict__ Ab, const unsigned short* __restrict__ Wt,
        signed char* __restrict__ C8, float* __restrict__ Ts, int M) {
    __shared__ unsigned short As[64 * 64];     // 8 KB
    __shared__ unsigned short Bs[128 * 64];    // 16 KB
    const int tid = threadIdx.x;
    const int lane = tid & 63;
    const int wave = tid >> 6;
    const int l15 = lane & 15;
    const int quad = lane >> 4;
    const int wm = wave & 1;
    const int wn = wave >> 1;

    const int bid = blockIdx.x;
    const int grp = bid >> 4;
    const int ii = bid & 15;
    const int xv = grp * 8 + (ii & 7);
    const int yv = ii >> 3;
    const int m0 = xv * 64;
    const int n0 = yv * 128;
    if (m0 >= M) return;

    float4v acc[2][4] = {};

    // staging lane geometry: 8 rows per wave-load, lane l -> row l>>3,
    // source 16B slot (l&7)^(l>>3)  (r0 % 8 == 0 so r&7 == l>>3)
    const int lrow = lane >> 3;
    const int lslot = (lane & 7) ^ lrow;

    const unsigned short* Bt = Wt + (size_t)n0 * 256;

    for (int kk = 0; kk < 256; kk += 64) {
        // A: 64 rows, 2 gload_lds per wave (16 rows/wave)
#pragma unroll
        for (int i = 0; i < 2; i++) {
            int r0 = wave * 16 + i * 8;
            int gm = m0 + r0 + lrow;
            if (gm >= M) gm = M - 1;         // clamp; garbage rows masked at store
            const unsigned short* gp = &Ab[(size_t)gm * 256 + kk + lslot * 8];
            __builtin_amdgcn_global_load_lds(
                (const __attribute__((address_space(1))) unsigned int*)gp,
                (__attribute__((address_space(3))) unsigned int*)&As[r0 * 64],
                16, 0, 0);
        }
        // B: 128 rows, 4 gload_lds per wave
#pragma unroll
        for (int i = 0; i < 4; i++) {
            int r0 = wave * 32 + i * 8;
            const unsigned short* gp = &Bt[(size_t)(r0 + lrow) * 256 + kk + lslot * 8];
            __builtin_amdgcn_global_load_lds(
                (const __attribute__((address_space(1))) unsigned int*)gp,
                (__attribute__((address_space(3))) unsigned int*)&Bs[r0 * 64],
                16, 0, 0);
        }
        __syncthreads();
#pragma unroll
        for (int ks = 0; ks < 64; ks += 32) {
            const int sl = (ks >> 3) + quad;   // 16B content slot
            short8 af[2], bf[4];
#pragma unroll
            for (int mi = 0; mi < 2; mi++) {
                int row = wm * 32 + mi * 16 + l15;
                af[mi] = *(const short8*)&As[row * 64 + 8 * (sl ^ (row & 7))];
            }
#pragma unroll
            for (int nj = 0; nj < 4; nj++) {
                int row = wn * 64 + nj * 16 + l15;
                bf[nj] = *(const short8*)&Bs[row * 64 + 8 * (sl ^ (row & 7))];
            }
#pragma unroll
            for (int mi = 0; mi < 2; mi++)
#pragma unroll
                for (int nj = 0; nj < 4; nj++)
                    acc[mi][nj] = __builtin_amdgcn_mfma_f32_16x16x32_bf16(
                        af[mi], bf[nj], acc[mi][nj], 0, 0, 0);
        }
        __syncthreads();
    }

    // ---- epilogue: per-row absmax over this block's 128 cols -> int8 ----
    float* pmax = (float*)As;              // [64][2]
    float* pinv = (float*)&As[512];        // [64]
#pragma unroll
    for (int mi = 0; mi < 2; mi++) {
#pragma unroll
        for (int r = 0; r < 4; r++) {
            float m = fabsf(acc[mi][0][r]);
            m = fmaxf(m, fabsf(acc[mi][1][r]));
            m = fmaxf(m, fabsf(acc[mi][2][r]));
            m = fmaxf(m, fabsf(acc[mi][3][r]));
            m = fmaxf(m, __shfl_xor(m, 1));
            m = fmaxf(m, __shfl_xor(m, 2));
            m = fmaxf(m, __shfl_xor(m, 4));
            m = fmaxf(m, __shfl_xor(m, 8));
            if (l15 == 0) pmax[(wm * 32 + mi * 16 + quad * 4 + r) * 2 + wn] = m;
        }
    }
    __syncthreads();
    if (tid < 64) {
        float m = fmaxf(pmax[tid * 2], pmax[tid * 2 + 1]);
        int grow = m0 + tid;
        if (grow < M) Ts[(size_t)grow * 2 + yv] = m * (1.f / 127.f);
        pinv[tid] = (m > 0.f) ? 127.f / m : 0.f;
    }
    __syncthreads();
#pragma unroll
    for (int mi = 0; mi < 2; mi++) {
#pragma unroll
        for (int r = 0; r < 4; r++) {
            int lr = wm * 32 + mi * 16 + quad * 4 + r;
            float inv = pinv[lr];
            int row = m0 + lr;
            if (row < M) {
#pragma unroll
                for (int nj = 0; nj < 4; nj++) {
                    int col = n0 + wn * 64 + nj * 16 + l15;
                    C8[(size_t)row * 256 + col] =
                        (signed char)__float2int_rn(acc[mi][nj][r] * inv);
                }
            }
        }
    }
}

// ---------------- aggregation (int8 gather, fp32 accum, bf16 out) ----------
template <int RELU>
__global__ __launch_bounds__(256) void agg_bf16_kernel(
        const signed char* __restrict__ T8, const float* __restrict__ Ts,
        const float* __restrict__ bias,
        const int* __restrict__ offs, const int* __restrict__ csr_src,
        const float* __restrict__ csr_nrm, const float* __restrict__ dis,
        unsigned short* __restrict__ out, int N) {
    int hw = threadIdx.x >> 5;                 // half-wave 0..7
    int l = threadIdx.x & 31;
    int v = blockIdx.x * 8 + hw;
    if (v >= N) return;
    int f8 = l * 8;
    int hh = l >> 4;                           // column half 0/1
    int beg = offs[v], end = offs[v + 1];
    float dv = dis[v];
    float w = dv * dv * Ts[(size_t)v * 2 + hh];
    float a[8];
    {
        schar8 q = *(const schar8*)&T8[(size_t)v * 256 + f8];
#pragma unroll
        for (int i = 0; i < 8; i++) a[i] = w * (float)q[i];
    }
    int e = beg;
    for (; e + 4 <= end; e += 4) {
        int s0 = csr_src[e],     s1 = csr_src[e + 1];
        int s2 = csr_src[e + 2], s3 = csr_src[e + 3];
        float n0 = csr_nrm[e]     * Ts[(size_t)s0 * 2 + hh];
        float n1 = csr_nrm[e + 1] * Ts[(size_t)s1 * 2 + hh];
        float n2 = csr_nrm[e + 2] * Ts[(size_t)s2 * 2 + hh];
        float n3 = csr_nrm[e + 3] * Ts[(size_t)s3 * 2 + hh];
        schar8 h0 = *(const schar8*)&T8[(size_t)s0 * 256 + f8];
        schar8 h1 = *(const schar8*)&T8[(size_t)s1 * 256 + f8];
        schar8 h2 = *(const schar8*)&T8[(size_t)s2 * 256 + f8];
        schar8 h3 = *(const schar8*)&T8[(size_t)s3 * 256 + f8];
#pragma unroll
        for (int i = 0; i < 8; i++)
            a[i] += n0 * (float)h0[i] + n1 * (float)h1[i]
                  + n2 * (float)h2[i] + n3 * (float)h3[i];
    }
    for (; e < end; e++) {
        int s = csr_src[e];
        float nm = csr_nrm[e] * Ts[(size_t)s * 2 + hh];
        schar8 h = *(const schar8*)&T8[(size_t)s * 256 + f8];
#pragma unroll
        for (int i = 0; i < 8; i++) a[i] += nm * (float)h[i];
    }
    float4 bv0 = *(const float4*)&bias[f8];
    float4 bv1 = *(const float4*)&bias[f8 + 4];
    a[0] += bv0.x; a[1] += bv0.y; a[2] += bv0.z; a[3] += bv0.w;
    a[4] += bv1.x; a[5] += bv1.y; a[6] += bv1.z; a[7] += bv1.w;
    if (RELU) {
#pragma unroll
        for (int i = 0; i < 8; i++) a[i] = fmaxf(a[i], 0.f);
    }
    uint4 o;
    o.x = (unsigned int)f2b(a[0]) | ((unsigned int)f2b(a[1]) << 16);
    o.y = (unsigned int)f2b(a[2]) | ((unsigned int)f2b(a[3]) << 16);
    o.z = (unsigned int)f2b(a[4]) | ((unsigned int)f2b(a[5]) << 16);
    o.w = (unsigned int)f2b(a[6]) | ((unsigned int)f2b(a[7]) << 16);
    *(uint4*)&out[(size_t)v * 256 + f8] = o;
}

// ---------------- weighted pool, two-stage (R12 proven) ----------------
__global__ __launch_bounds__(256) void wpool_partial(
        const unsigned short* __restrict__ H, const float* __restrict__ dis,
        const float* __restrict__ tsum, float* __restrict__ partial, int N) {
    int tid = threadIdx.x;
    int f8 = (tid & 31) * 8;
    int rg = tid >> 5;
    float a[8] = {};
    for (int r = blockIdx.x * 8 + rg; r < N; r += gridDim.x * 8) {
        float s = dis[r] * (dis[r] + tsum[r]);
        short8 h = *(const short8*)&H[(size_t)r * 256 + f8];
#pragma unroll
        for (int i = 0; i < 8; i++) a[i] += s * b2f((unsigned short)h[i]);
    }
    __shared__ float red[8 * 256];
#pragma unroll
    for (int i = 0; i < 8; i++) red[rg * 256 + f8 + i] = a[i];
    __syncthreads();
    for (int s = 4; s > 0; s >>= 1) {
        if (rg < s) {
#pragma unroll
            for (int i = 0; i < 8; i++)
                red[rg * 256 + f8 + i] += red[(rg + s) * 256 + f8 + i];
        }
        __syncthreads();
    }
    partial[(size_t)blockIdx.x * 256 + tid] = red[tid];
}

__global__ void wpool_reduce(const float* __restrict__ partial, float* __restrict__ acc) {
    int f = threadIdx.x;
    int p0 = blockIdx.x * 32;
    float a = 0.f;
#pragma unroll
    for (int p = 0; p < 32; p++) a += partial[(size_t)(p0 + p) * 256 + f];
    atomicAdd(&acc[f], a);
}

__global__ void final_kernel(const float* __restrict__ acc, const float* __restrict__ W4,
                             const float* __restrict__ b4, float* __restrict__ out, int N) {
    __shared__ float red[128];
    int c = threadIdx.x;
    float p = (float)N * b4[c];
    for (int k = 0; k < 256; k++) p += acc[k] * W4[k * 128 + c];
    out[c] = p;
    red[c] = p;
    __syncthreads();
    for (int s = 64; s > 0; s >>= 1) {
        if (c < s) red[c] = fmaxf(red[c], red[c + s]);
        __syncthreads();
    }
    float m = red[0];
    __syncthreads();
    red[c] = expf(p - m);
    __syncthreads();
    for (int s = 64; s > 0; s >>= 1) {
        if (c < s) red[c] += red[c + s];
        __syncthreads();
    }
    float lse = m + logf(red[0]);
    out[128 + c] = p - lse;
}

extern "C" void kernel_launch(void* const* d_in, const int* in_sizes, int n_in,
                              void* d_out, int out_size, void* d_ws, size_t ws_size,
                              hipStream_t stream) {
    const float* x  = (const float*)d_in[0];
    const int*   ei = (const int*)d_in[1];
    const float* W1 = (const float*)d_in[2];
    const float* b1 = (const float*)d_in[3];
    const float* W2 = (const float*)d_in[4];
    const float* b2 = (const float*)d_in[5];
    const float* W3 = (const float*)d_in[6];
    const float* b3 = (const float*)d_in[7];
    const float* W4 = (const float*)d_in[8];
    const float* b4 = (const float*)d_in[9];

    const int N = in_sizes[0] / 256;
    const int E = in_sizes[1] / 2;
    const int* src = ei;
    const int* dst = ei + E;

    char* p = (char*)d_ws;
    auto alloc = [&](size_t bytes) {
        char* r = p;
        p += (bytes + 255) & ~(size_t)255;
        return r;
    };
    int*            cnt     = (int*)alloc((size_t)N * 4);
    int*            offs    = (int*)alloc((size_t)(N + 1) * 4);
    int*            cursor  = (int*)alloc((size_t)N * 4);
    float*          dis     = (float*)alloc((size_t)N * 4);
    float*          tsum    = (float*)alloc((size_t)N * 4);
    int*            bsum    = (int*)alloc(1024 * 4);
    int*            csr_src = (int*)alloc((size_t)E * 4);
    float*          csr_nrm = (float*)alloc((size_t)E * 4);
    unsigned short* Wt1     = (unsigned short*)alloc(256 * 256 * 2);
    unsigned short* Wt2     = (unsigned short*)alloc(256 * 256 * 2);
    unsigned short* Wt3     = (unsigned short*)alloc(256 * 256 * 2);
    unsigned short* xb      = (unsigned short*)alloc((size_t)N * 256 * 2);
    signed char*    T8      = (signed char*)alloc((size_t)N * 256);
    float*          Ts      = (float*)alloc((size_t)N * 2 * 4);
    unsigned short* Abuf    = (unsigned short*)alloc((size_t)N * 256 * 2);
    float*          partial = (float*)alloc((size_t)1024 * 256 * 4);
    float*          accbuf  = (float*)alloc(256 * 4);

    // ---- graph preprocessing + dtype conversion ----
    int eb = (E + 255) / 256;
    int nb = (N + 255) / 256;  // 196; finalize's bsum scan assumes nb <= 256
    int ncvt = (N * 32 + 255) / 256;   // x->bf16, 8 elems/thread
    zero_convert_kernel<<<nb + 768 + ncvt, 256, 0, stream>>>(
        cnt, tsum, accbuf, W1, W2, W3, Wt1, Wt2, Wt3, x, xb, N, nb);
    count_kernel<<<eb, 256, 0, stream>>>(dst, cnt, E);
    blocksum_kernel<<<nb, 256, 0, stream>>>(cnt, bsum, N);
    finalize_kernel<<<nb, 256, 0, stream>>>(cnt, bsum, offs, cursor, dis, N, E, nb);
    scatter_outsum_kernel<<<eb, 256, 0, stream>>>(src, dst, dis, cursor, csr_src,
                                                  csr_nrm, tsum, E);

    // ---- layers 1..3 ----
    int mtiles = (N + 63) / 64;              // 782
    int ggrid = ((mtiles + 7) / 8) * 16;     // XCD-paired 1-D grid (1568)
    int ab = (N + 7) / 8;
    gemm_bf16_kernel<<<ggrid, 256, 0, stream>>>(xb, Wt1, T8, Ts, N);
    agg_bf16_kernel<1><<<ab, 256, 0, stream>>>(T8, Ts, b1, offs, csr_src, csr_nrm, dis, Abuf, N);
    gemm_bf16_kernel<<<ggrid, 256, 0, stream>>>(Abuf, Wt2, T8, Ts, N);
    agg_bf16_kernel<1><<<ab, 256, 0, stream>>>(T8, Ts, b2, offs, csr_src, csr_nrm, dis, Abuf, N);
    gemm_bf16_kernel<<<ggrid, 256, 0, stream>>>(Abuf, Wt3, T8, Ts, N);
    agg_bf16_kernel<1><<<ab, 256, 0, stream>>>(T8, Ts, b3, offs, csr_src, csr_nrm, dis, Abuf, N);

    // ---- collapsed layer 4 + pool + log_softmax ----
    wpool_partial<<<1024, 256, 0, stream>>>(Abuf, dis, tsum, partial, N);
    wpool_reduce<<<32, 256, 0, stream>>>(partial, accbuf);
    final_kernel<<<1, 128, 0, stream>>>(accbuf, W4, b4, (float*)d_out, N);
}